// Round 6
// baseline (15490.208 us; speedup 1.0000x reference)
//
#include <hip/hip_runtime.h>
#include <hip/hip_bf16.h>

// GRU B=64 T=1024 D=U=512, reset_after=true. fp32 in/out, bf16 MFMA internally.
//
// Phase 2 v4: tag-in-data h broadcast. h exchanged as u64 {tag32=t+1, bf16x2}
// in an 8-deep ring; consumers poll their own data words and validate tags
// (no flag hop, no store drain, no __syncthreads). Ring-reuse back-pressure
// via advisory per-wave progress flags checked against t-7 (7-step slack).
//
// ws layout (bytes):
//   [0,512)                  flags[128] per-wave progress (memset each launch)
//   [135168, +1048576)       h ring u64[8][64][256]  (OVERLAYS Wt after xm_gemm;
//                            memset after xm_gemm each launch)
//   [135168, +1572864)       Wt  bf16 [1536][512]  (dead after xm_gemm)
//   [1708032, +1572864)      Rt  bf16 [1536][512]
//   [3280896, +201326592)    XM  bf16 [T*64][1536] (x@W + b_i), row = t*64+b

typedef __attribute__((ext_vector_type(8))) short short8;
typedef __attribute__((ext_vector_type(4))) float f32x4;
typedef __attribute__((ext_vector_type(4))) unsigned int u32x4;

__device__ __forceinline__ unsigned short f2bf(float f) {
  unsigned u = __float_as_uint(f);
  u += 0x7FFFu + ((u >> 16) & 1u);   // RNE
  return (unsigned short)(u >> 16);
}
__device__ __forceinline__ float bf2f(unsigned short s) {
  return __uint_as_float(((unsigned)s) << 16);
}

// ---------------- Phase 0: transpose fp32 [R][C] -> bf16 [C][R] ----------------
__global__ void transpose_cast(const float* __restrict__ src,
                               unsigned short* __restrict__ dst,
                               int R, int C) {
  __shared__ float tile[32][33];
  int c0 = blockIdx.x * 32, r0 = blockIdx.y * 32;
  int tx = threadIdx.x, ty = threadIdx.y;
#pragma unroll
  for (int i = 0; i < 4; i++) {
    tile[ty + i * 8][tx] = src[(size_t)(r0 + ty + i * 8) * C + c0 + tx];
  }
  __syncthreads();
#pragma unroll
  for (int i = 0; i < 4; i++) {
    dst[(size_t)(c0 + ty + i * 8) * R + r0 + tx] = f2bf(tile[tx][ty + i * 8]);
  }
}

// ---------------- Phase 1: XM = x @ W + b_i  (bf16 out) ----------------
__global__ __launch_bounds__(256) void xm_gemm(const float* __restrict__ x,
                                               const unsigned short* __restrict__ Wt,
                                               const float* __restrict__ bias,
                                               unsigned short* __restrict__ XM) {
  __shared__ unsigned short As[128][72];
  __shared__ unsigned short Bs[128][72];
  const int tid = threadIdx.x;
  const int bm = blockIdx.x;   // 512
  const int bn = blockIdx.y;   // 12
  const int wave = tid >> 6, lane = tid & 63;
  const int moff = (wave & 1) * 64, noff = (wave >> 1) * 64;

  f32x4 acc[4][4];
#pragma unroll
  for (int mt = 0; mt < 4; mt++)
#pragma unroll
    for (int nt = 0; nt < 4; nt++) acc[mt][nt] = (f32x4){0.f, 0.f, 0.f, 0.f};

  const int r = tid >> 1;
  const int kb = (tid & 1) * 32;
  const int rg = bm * 128 + r;
  const int bb = rg & 63, tt = rg >> 6;

  for (int k0 = 0; k0 < 512; k0 += 64) {
    const f32x4* xp4 = (const f32x4*)(x + ((size_t)bb * 1024 + tt) * 512 + k0 + kb);
#pragma unroll
    for (int j = 0; j < 4; j++) {
      f32x4 lo = xp4[2 * j];
      f32x4 hi = xp4[2 * j + 1];
      union { unsigned short us[8]; short8 v; } u;
      u.us[0] = f2bf(lo[0]); u.us[1] = f2bf(lo[1]); u.us[2] = f2bf(lo[2]); u.us[3] = f2bf(lo[3]);
      u.us[4] = f2bf(hi[0]); u.us[5] = f2bf(hi[1]); u.us[6] = f2bf(hi[2]); u.us[7] = f2bf(hi[3]);
      *(short8*)&As[r][kb + j * 8] = u.v;
    }
    const short8* wp8 = (const short8*)(Wt + (size_t)(bn * 128 + r) * 512 + k0 + kb);
#pragma unroll
    for (int j = 0; j < 4; j++) *(short8*)&Bs[r][kb + j * 8] = wp8[j];
    __syncthreads();

#pragma unroll
    for (int kk = 0; kk < 2; kk++) {
      short8 a[4], b[4];
#pragma unroll
      for (int mt = 0; mt < 4; mt++)
        a[mt] = *(const short8*)&As[moff + mt * 16 + (lane & 15)][kk * 32 + (lane >> 4) * 8];
#pragma unroll
      for (int nt = 0; nt < 4; nt++)
        b[nt] = *(const short8*)&Bs[noff + nt * 16 + (lane & 15)][kk * 32 + (lane >> 4) * 8];
#pragma unroll
      for (int mt = 0; mt < 4; mt++)
#pragma unroll
        for (int nt = 0; nt < 4; nt++)
          acc[mt][nt] = __builtin_amdgcn_mfma_f32_16x16x32_bf16(a[mt], b[nt], acc[mt][nt], 0, 0, 0);
    }
    __syncthreads();
  }

#pragma unroll
  for (int nt = 0; nt < 4; nt++) {
    const int cg = bn * 128 + noff + nt * 16 + (lane & 15);
    const float bi = bias[cg];
#pragma unroll
    for (int mt = 0; mt < 4; mt++) {
      const int rg2 = bm * 128 + moff + mt * 16 + (lane >> 4) * 4;
#pragma unroll
      for (int i = 0; i < 4; i++)
        XM[(size_t)(rg2 + i) * 1536 + cg] = f2bf(acc[mt][nt][i] + bi);
    }
  }
}

// ---------------- Phase 2: recurrence, tag-validated h broadcast ----------------
// 32 blocks x 256 threads; waves fully independent (no __syncthreads in loop).
// Wave (blk,w) owns units [blk*16,+16) for batches [w*16,+16).
// Ring entry (slot=tag&7, batch, unitpair): u64 {hi32=tag, lo32=bf16(u)|bf16(u+1)<<16}.
__global__ __launch_bounds__(256, 1) void gru_rec(const unsigned short* __restrict__ Rt,
                                                  const unsigned short* __restrict__ XM,
                                                  const float* __restrict__ bias,
                                                  unsigned long long* ring,
                                                  unsigned int* flags,
                                                  float* __restrict__ out) {
  const int tid = threadIdx.x;
  const int lane = tid & 63;
  const int wave = tid >> 6;
  const int blk = blockIdx.x;
  const int u0 = blk * 16;
  const int col = lane & 15;
  const int krow = lane >> 4;
  const int wid = blk * 4 + wave;     // 0..127

  // weights: Bf[gate][ks] = Rt[gate*512+u0+col][ks*32+krow*8 ..+8]
  short8 Bf[3][16];
#pragma unroll
  for (int g = 0; g < 3; g++)
#pragma unroll
    for (int ks = 0; ks < 16; ks++)
      Bf[g][ks] = *(const short8*)(Rt + (size_t)(g * 512 + u0 + col) * 512 + ks * 32 + krow * 8);

  const float br0 = bias[1536 + 0 * 512 + u0 + col];
  const float br1 = bias[1536 + 1 * 512 + u0 + col];
  const float br2 = bias[1536 + 2 * 512 + u0 + col];

  float hreg[4] = {0.f, 0.f, 0.f, 0.f};

  unsigned short xc[3][4], xn[3][4];
#pragma unroll
  for (int g = 0; g < 3; g++)
#pragma unroll
    for (int i = 0; i < 4; i++) {
      int batch = wave * 16 + krow * 4 + i;
      xc[g][i] = XM[(size_t)batch * 1536 + g * 512 + u0 + col];
    }

#pragma unroll 1
  for (int t = 0; t < 1024; ++t) {
    // advisory progress snapshot (for ring back-pressure), issued early so its
    // latency hides under the Af poll + MFMA.
    unsigned fl0 = __hip_atomic_load(&flags[lane * 2], __ATOMIC_RELAXED, __HIP_MEMORY_SCOPE_AGENT);
    unsigned fl1 = __hip_atomic_load(&flags[lane * 2 + 1], __ATOMIC_RELAXED, __HIP_MEMORY_SCOPE_AGENT);

    f32x4 acc0 = (f32x4){0.f, 0.f, 0.f, 0.f};
    f32x4 acc1 = acc0, acc2 = acc0;
    unsigned long long bl = ~0ull;

    if (t > 0) {
      // consumer: poll own data words, validate tags == t.
      const unsigned long long* hp =
          ring + ((size_t)((t & 7) * 64 + wave * 16 + col) * 256 + krow * 4);
      const unsigned tagv = (unsigned)t;
      u32x4 q[32];                    // q[ks*2+h] = 16B at byte ks*128 + h*16
      for (int att = 0;; ++att) {
        if (att == 0) {
          asm volatile(
              "global_load_dwordx4 %0, %8, off sc0 sc1\n\t"
              "global_load_dwordx4 %1, %8, off offset:16 sc0 sc1\n\t"
              "global_load_dwordx4 %2, %8, off offset:128 sc0 sc1\n\t"
              "global_load_dwordx4 %3, %8, off offset:144 sc0 sc1\n\t"
              "global_load_dwordx4 %4, %8, off offset:256 sc0 sc1\n\t"
              "global_load_dwordx4 %5, %8, off offset:272 sc0 sc1\n\t"
              "global_load_dwordx4 %6, %8, off offset:384 sc0 sc1\n\t"
              "global_load_dwordx4 %7, %8, off offset:400 sc0 sc1"
              : "=&v"(q[0]), "=&v"(q[1]), "=&v"(q[2]), "=&v"(q[3]),
                "=&v"(q[4]), "=&v"(q[5]), "=&v"(q[6]), "=&v"(q[7])
              : "v"(hp) : "memory");
          asm volatile(
              "global_load_dwordx4 %0, %8, off offset:512 sc0 sc1\n\t"
              "global_load_dwordx4 %1, %8, off offset:528 sc0 sc1\n\t"
              "global_load_dwordx4 %2, %8, off offset:640 sc0 sc1\n\t"
              "global_load_dwordx4 %3, %8, off offset:656 sc0 sc1\n\t"
              "global_load_dwordx4 %4, %8, off offset:768 sc0 sc1\n\t"
              "global_load_dwordx4 %5, %8, off offset:784 sc0 sc1\n\t"
              "global_load_dwordx4 %6, %8, off offset:896 sc0 sc1\n\t"
              "global_load_dwordx4 %7, %8, off offset:912 sc0 sc1"
              : "=&v"(q[8]), "=&v"(q[9]), "=&v"(q[10]), "=&v"(q[11]),
                "=&v"(q[12]), "=&v"(q[13]), "=&v"(q[14]), "=&v"(q[15])
              : "v"(hp) : "memory");
          asm volatile(
              "global_load_dwordx4 %0, %8, off offset:1024 sc0 sc1\n\t"
              "global_load_dwordx4 %1, %8, off offset:1040 sc0 sc1\n\t"
              "global_load_dwordx4 %2, %8, off offset:1152 sc0 sc1\n\t"
              "global_load_dwordx4 %3, %8, off offset:1168 sc0 sc1\n\t"
              "global_load_dwordx4 %4, %8, off offset:1280 sc0 sc1\n\t"
              "global_load_dwordx4 %5, %8, off offset:1296 sc0 sc1\n\t"
              "global_load_dwordx4 %6, %8, off offset:1408 sc0 sc1\n\t"
              "global_load_dwordx4 %7, %8, off offset:1424 sc0 sc1"
              : "=&v"(q[16]), "=&v"(q[17]), "=&v"(q[18]), "=&v"(q[19]),
                "=&v"(q[20]), "=&v"(q[21]), "=&v"(q[22]), "=&v"(q[23])
              : "v"(hp) : "memory");
          asm volatile(
              "global_load_dwordx4 %0, %8, off offset:1536 sc0 sc1\n\t"
              "global_load_dwordx4 %1, %8, off offset:1552 sc0 sc1\n\t"
              "global_load_dwordx4 %2, %8, off offset:1664 sc0 sc1\n\t"
              "global_load_dwordx4 %3, %8, off offset:1680 sc0 sc1\n\t"
              "global_load_dwordx4 %4, %8, off offset:1792 sc0 sc1\n\t"
              "global_load_dwordx4 %5, %8, off offset:1808 sc0 sc1\n\t"
              "global_load_dwordx4 %6, %8, off offset:1920 sc0 sc1\n\t"
              "global_load_dwordx4 %7, %8, off offset:1936 sc0 sc1"
              : "=&v"(q[24]), "=&v"(q[25]), "=&v"(q[26]), "=&v"(q[27]),
                "=&v"(q[28]), "=&v"(q[29]), "=&v"(q[30]), "=&v"(q[31])
              : "v"(hp) : "memory");
          asm volatile("s_waitcnt vmcnt(0)" ::: "memory");
          __builtin_amdgcn_sched_barrier(0);
        } else {
          // proven-visibility fallback: per-u64 agent atomic loads
#pragma unroll
          for (int ks = 0; ks < 16; ++ks)
#pragma unroll
            for (int h = 0; h < 2; ++h) {
              unsigned long long a = __hip_atomic_load(hp + ks * 16 + h * 2,
                                                       __ATOMIC_RELAXED, __HIP_MEMORY_SCOPE_AGENT);
              unsigned long long b = __hip_atomic_load(hp + ks * 16 + h * 2 + 1,
                                                       __ATOMIC_RELAXED, __HIP_MEMORY_SCOPE_AGENT);
              q[ks * 2 + h] = (u32x4){(unsigned)a, (unsigned)(a >> 32),
                                      (unsigned)b, (unsigned)(b >> 32)};
            }
        }
        unsigned bad = 0;
#pragma unroll
        for (int i = 0; i < 32; ++i) bad |= (q[i].y ^ tagv) | (q[i].w ^ tagv);
        bl = __ballot((int)(bad == 0));
        if (bl == ~0ull) break;
        __builtin_amdgcn_s_sleep(2);
      }

      // publish progress early (advisory; data-dep on bl keeps it after the loads)
      if (t < 1023 && lane == 0)
        __hip_atomic_store(&flags[wid], (unsigned)t + (unsigned)(bl >> 63) - 1u,
                           __ATOMIC_RELAXED, __HIP_MEMORY_SCOPE_AGENT);

      short8 Af[16];
#pragma unroll
      for (int ks = 0; ks < 16; ++ks) {
        u32x4 d = (u32x4){q[ks * 2].x, q[ks * 2].z, q[ks * 2 + 1].x, q[ks * 2 + 1].z};
        Af[ks] = __builtin_bit_cast(short8, d);
      }
#pragma unroll
      for (int ks = 0; ks < 16; ++ks) {
        acc0 = __builtin_amdgcn_mfma_f32_16x16x32_bf16(Af[ks], Bf[0][ks], acc0, 0, 0, 0);
        acc1 = __builtin_amdgcn_mfma_f32_16x16x32_bf16(Af[ks], Bf[1][ks], acc1, 0, 0, 0);
        acc2 = __builtin_amdgcn_mfma_f32_16x16x32_bf16(Af[ks], Bf[2][ks], acc2, 0, 0, 0);
      }
    }

    // gates (fp32); identical arithmetic to r5.
#pragma unroll
    for (int i = 0; i < 4; i++) {
      float hz = acc0[i] + br0;
      float hr = acc1[i] + br1;
      float hh = acc2[i] + br2;
      float xz = bf2f(xc[0][i]);
      float xr = bf2f(xc[1][i]);
      float xh = bf2f(xc[2][i]);
      float z = 1.f / (1.f + __expf(-(xz + hz)));
      float r = 1.f / (1.f + __expf(-(xr + hr)));
      float y = xh + r * hh;
      float ay = fabsf(y);
      float e = __expf(-2.f * ay);
      float ca = (1.f - e) / (1.f + e);
      ca = (y < 0.f) ? -ca : ca;
      hreg[i] = z * hreg[i] + (1.f - z) * ca;
    }

    if (t < 1023) {
      // ring back-pressure: before storing tag t+1 (slot (t+1)&7, overwrites
      // tag t-7), all 128 waves must have consumed tag t-7. 7-step slack =>
      // the startup snapshot almost always passes; spin is the rare path.
      if (t >= 8) {
        const unsigned need = (unsigned)(t - 7);
        for (;;) {
          if (__all((int)(fl0 >= need && fl1 >= need))) break;
          __builtin_amdgcn_s_sleep(2);
          fl0 = __hip_atomic_load(&flags[lane * 2], __ATOMIC_RELAXED, __HIP_MEMORY_SCOPE_AGENT);
          fl1 = __hip_atomic_load(&flags[lane * 2 + 1], __ATOMIC_RELAXED, __HIP_MEMORY_SCOPE_AGENT);
        }
      }
      const int slot = (t + 1) & 7;
      const unsigned long long tagbits = ((unsigned long long)(unsigned)(t + 1)) << 32;
#pragma unroll
      for (int i = 0; i < 4; i++) {
        int batch = wave * 16 + krow * 4 + i;
        float other = __shfl_xor(hreg[i], 1);
        if ((col & 1) == 0) {
          unsigned d = (unsigned)f2bf(hreg[i]) | ((unsigned)f2bf(other) << 16);
          __hip_atomic_store(ring + (size_t)(slot * 64 + batch) * 256 + ((u0 + col) >> 1),
                             tagbits | d, __ATOMIC_RELAXED, __HIP_MEMORY_SCOPE_AGENT);
        }
      }
    }

    // XM prefetch for next step (hides HBM latency under next poll/MFMA)
    const int tn = (t < 1023) ? t + 1 : 1023;
#pragma unroll
    for (int g = 0; g < 3; g++)
#pragma unroll
      for (int i = 0; i < 4; i++) {
        int batch = wave * 16 + krow * 4 + i;
        xn[g][i] = XM[(size_t)(tn * 64 + batch) * 1536 + g * 512 + u0 + col];
      }
#pragma unroll
    for (int g = 0; g < 3; g++)
#pragma unroll
      for (int i = 0; i < 4; i++) xc[g][i] = xn[g][i];
  }

#pragma unroll
  for (int i = 0; i < 4; i++) {
    int batch = wave * 16 + krow * 4 + i;
    out[(size_t)batch * 512 + u0 + col] = hreg[i];
  }
}

// ---------------- launch ----------------
extern "C" void kernel_launch(void* const* d_in, const int* in_sizes, int n_in,
                              void* d_out, int out_size, void* d_ws, size_t ws_size,
                              hipStream_t stream) {
  const float* x = (const float*)d_in[0];       // [64][1024][512]
  const float* W = (const float*)d_in[1];       // [512][1536]
  const float* R = (const float*)d_in[2];       // [512][1536]
  const float* bias = (const float*)d_in[3];    // [2][1536]
  float* out = (float*)d_out;

  char* ws = (char*)d_ws;
  unsigned int* flags = (unsigned int*)(ws + 0);
  unsigned short* Wt = (unsigned short*)(ws + 135168);
  unsigned long long* ring = (unsigned long long*)(ws + 135168);  // overlays Wt
  unsigned short* Rt = (unsigned short*)(ws + 1708032);
  unsigned short* XM = (unsigned short*)(ws + 3280896);

  hipMemsetAsync(flags, 0, 4096, stream);
  transpose_cast<<<dim3(48, 16), dim3(32, 8), 0, stream>>>(W, Wt, 512, 1536);
  transpose_cast<<<dim3(48, 16), dim3(32, 8), 0, stream>>>(R, Rt, 512, 1536);
  xm_gemm<<<dim3(512, 12), dim3(256), 0, stream>>>(x, Wt, bias, XM);
  // Wt is dead now; clear the ring that overlays it (kills stale tags from
  // prior graph replays; kernel-boundary release makes the zeros MALL-visible).
  hipMemsetAsync(ring, 0, 8ull * 64 * 256 * 8, stream);
  gru_rec<<<dim3(32), dim3(256), 0, stream>>>(Rt, XM, bias, ring, flags, out);
}